// Round 1
// baseline (126.614 us; speedup 1.0000x reference)
//
#include <hip/hip_runtime.h>
#include <math.h>

#define NB 131072
#define NM 32
#define EC 2.7182818284590452f
#define TS 0.17677669529663687f   // 1/sqrt(32)
#define L2E 1.4426950408889634f
#define LN2F 0.6931471805599453f

// ws layout (floats):
//   [0, 1024)        : Gsym (symmetrized Gamma, row-major)
//   [1024, 1056)     : mode_min[c] - EC   (pre-subtracted)
//   [2048, 2048+8192): per-block partial column mins (256 blocks x 32 cols)
// total 40 KiB of d_ws used.

#if __has_builtin(__builtin_amdgcn_exp2f)
__device__ __forceinline__ float fexp2(float x) { return __builtin_amdgcn_exp2f(x); }
#else
__device__ __forceinline__ float fexp2(float x) { return exp2f(x); }
#endif
#if __has_builtin(__builtin_amdgcn_logf)
__device__ __forceinline__ float flog2(float x) { return __builtin_amdgcn_logf(x); }
#else
__device__ __forceinline__ float flog2(float x) { return __log2f(x); }
#endif

// ---------------- Kernel A: per-block partial column minima ----------------
// 256 blocks x 256 threads; each thread consumes 16 float4s (whole phi).
// float4 index f covers columns 4*(f%8)..+3; f%8 is constant per thread.
__global__ __launch_bounds__(256) void k_min(const float* __restrict__ phi,
                                             float* __restrict__ ws) {
    __shared__ float sm[1024];
    const int tid = threadIdx.x;
    const int g = blockIdx.x * 256 + tid;
    const float4* __restrict__ p4 = (const float4*)phi;
    float4 m = p4[g];
    #pragma unroll
    for (int k = 1; k < 16; ++k) {
        float4 v = p4[g + k * 65536];
        m.x = fminf(m.x, v.x); m.y = fminf(m.y, v.y);
        m.z = fminf(m.z, v.z); m.w = fminf(m.w, v.w);
    }
    sm[tid * 4 + 0] = m.x; sm[tid * 4 + 1] = m.y;
    sm[tid * 4 + 2] = m.z; sm[tid * 4 + 3] = m.w;
    __syncthreads();
    // tree-reduce; all strides are multiples of 8 so column groups (tid%8) match
    #pragma unroll
    for (int s = 128; s >= 8; s >>= 1) {
        if (tid < s) {
            sm[tid * 4 + 0] = fminf(sm[tid * 4 + 0], sm[(tid + s) * 4 + 0]);
            sm[tid * 4 + 1] = fminf(sm[tid * 4 + 1], sm[(tid + s) * 4 + 1]);
            sm[tid * 4 + 2] = fminf(sm[tid * 4 + 2], sm[(tid + s) * 4 + 2]);
            sm[tid * 4 + 3] = fminf(sm[tid * 4 + 3], sm[(tid + s) * 4 + 3]);
        }
        __syncthreads();
    }
    if (tid < 8) {
        #pragma unroll
        for (int s2 = 0; s2 < 4; ++s2)
            ws[2048 + blockIdx.x * 32 + tid * 4 + s2] = sm[tid * 4 + s2];
    }
}

// ------- Kernel B: final min reduce + Gamma symmetrization into ws --------
__global__ __launch_bounds__(64) void k_prep(const float* __restrict__ Gamma,
                                             float* __restrict__ ws) {
    __shared__ float sm[64];
    const int tid = threadIdx.x;
    const int c = tid & 31, h = tid >> 5;
    float m = INFINITY;
    #pragma unroll 8
    for (int b = h * 128; b < (h + 1) * 128; ++b)
        m = fminf(m, ws[2048 + b * 32 + c]);
    sm[tid] = m;
    __syncthreads();
    if (tid < 32) ws[1024 + tid] = fminf(sm[tid], sm[tid + 32]) - EC;
    // Gsym[i][j] = Gamma[min(i,j), max(i,j)]
    #pragma unroll
    for (int k = 0; k < 16; ++k) {
        int idx = tid + 64 * k;
        int i = idx >> 5, j = idx & 31;
        int lo = min(i, j), hi = i + j - lo;
        ws[idx] = Gamma[lo * 32 + hi];
    }
}

// ---------------- Kernel C: main (row-per-thread) ----------------
// 2048 blocks x 64 threads (1 wave/block). Each lane owns one row:
// loads its 32 phi values, computes L[32] = log2(phic) in registers,
// then the 32x32 energy loop with Gsym/w as wave-uniform scalar loads.
// L_i for runtime i comes from a conflict-free (stride-65) LDS mirror;
// x_i = -t*energy_i round-trips through LDS to become statically indexed.
__global__ __launch_bounds__(64, 2) void k_main(const float* __restrict__ phi,
                                                const float* __restrict__ w,
                                                const float* __restrict__ ws,
                                                float* __restrict__ out) {
    __shared__ float sL[32 * 65];
    __shared__ float sX[32 * 65];
    const int lane = threadIdx.x;
    const size_t row = (size_t)blockIdx.x * 64 + lane;
    const float* __restrict__ pr = phi + row * NM;
    const float* __restrict__ mme = ws + 1024;   // mode_min - e (uniform)

    float L[32];
    #pragma unroll
    for (int k = 0; k < 8; ++k) {
        float4 v = ((const float4*)pr)[k];
        // phic = max(phi - mode_min + e, e) = max(phi - (mode_min - e), e)
        float a0 = fmaxf(v.x - mme[4 * k + 0], EC);
        float a1 = fmaxf(v.y - mme[4 * k + 1], EC);
        float a2 = fmaxf(v.z - mme[4 * k + 2], EC);
        float a3 = fmaxf(v.w - mme[4 * k + 3], EC);
        L[4 * k + 0] = flog2(a0); L[4 * k + 1] = flog2(a1);
        L[4 * k + 2] = flog2(a2); L[4 * k + 3] = flog2(a3);
    }
    #pragma unroll
    for (int j = 0; j < 32; ++j) sL[j * 65 + lane] = L[j];
    __syncthreads();

    for (int i = 0; i < 32; ++i) {
        const float Li = sL[i * 65 + lane];
        const float* __restrict__ g = ws + i * 32;   // uniform -> s_load
        float acc0 = 0.f, acc1 = 0.f, acc2 = 0.f, acc3 = 0.f;
        #pragma unroll
        for (int j = 0; j < 32; j += 4) {
            // phic_i^g * phic_j^(1-g) = 2^(L_j + g*(L_i - L_j))
            acc0 += fexp2(fmaf(g[j + 0], Li - L[j + 0], L[j + 0]));
            acc1 += fexp2(fmaf(g[j + 1], Li - L[j + 1], L[j + 1]));
            acc2 += fexp2(fmaf(g[j + 2], Li - L[j + 2], L[j + 2]));
            acc3 += fexp2(fmaf(g[j + 3], Li - L[j + 3], L[j + 3]));
        }
        // full sum's diagonal term == phic_i, so off-sum + (1+w)*phic = full + w*phic
        const float e = ((acc0 + acc1) + (acc2 + acc3)) + w[i] * fexp2(Li);
        sX[i * 65 + lane] = -TS * e;
    }
    __syncthreads();

    float xs[32];
    #pragma unroll
    for (int i = 0; i < 32; ++i) xs[i] = sX[i * 65 + lane];
    float m = xs[0];
    #pragma unroll
    for (int i = 1; i < 32; ++i) m = fmaxf(m, xs[i]);
    float p[32];
    float s = 0.f;
    #pragma unroll
    for (int i = 0; i < 32; ++i) { p[i] = fexp2((xs[i] - m) * L2E); s += p[i]; }
    const float inv = 1.0f / s;
    const float lns = flog2(s) * LN2F;   // ln(s)

    float* __restrict__ oa = out + row * NM;
    float* __restrict__ ol = out + (size_t)NB * NM + row * NM;
    #pragma unroll
    for (int k = 0; k < 8; ++k) {
        float4 a4 = { p[4 * k + 0] * inv, p[4 * k + 1] * inv,
                      p[4 * k + 2] * inv, p[4 * k + 3] * inv };
        float4 l4 = { (xs[4 * k + 0] - m) - lns, (xs[4 * k + 1] - m) - lns,
                      (xs[4 * k + 2] - m) - lns, (xs[4 * k + 3] - m) - lns };
        ((float4*)oa)[k] = a4;
        ((float4*)ol)[k] = l4;
    }
}

extern "C" void kernel_launch(void* const* d_in, const int* in_sizes, int n_in,
                              void* d_out, int out_size, void* d_ws, size_t ws_size,
                              hipStream_t stream) {
    (void)in_sizes; (void)n_in; (void)out_size; (void)ws_size;
    const float* phi   = (const float*)d_in[0];
    const float* Gamma = (const float*)d_in[1];
    const float* w     = (const float*)d_in[2];
    float* out = (float*)d_out;
    float* wsf = (float*)d_ws;

    k_min<<<256, 256, 0, stream>>>(phi, wsf);
    k_prep<<<1, 64, 0, stream>>>(Gamma, wsf);
    k_main<<<2048, 64, 0, stream>>>(phi, w, wsf, out);
}

// Round 2
// 109.917 us; speedup vs baseline: 1.1519x; 1.1519x over previous
//
#include <hip/hip_runtime.h>
#include <math.h>

#define NB 131072
#define NM 32
#define EC 2.7182818284590452f
#define TS 0.17677669529663687f   // 1/sqrt(32)
#define L2E 1.4426950408889634f
#define LN2F 0.6931471805599453f

// ws layout (floats):
//   [0, 1024)        : Gsym (symmetrized Gamma, row-major)
//   [1024, 1056)     : mode_min[c] - EC   (pre-subtracted)
//   [2048, 2048+8192): per-block partial column mins (256 blocks x 32 cols)

#if __has_builtin(__builtin_amdgcn_exp2f)
__device__ __forceinline__ float fexp2(float x) { return __builtin_amdgcn_exp2f(x); }
#else
__device__ __forceinline__ float fexp2(float x) { return exp2f(x); }
#endif
#if __has_builtin(__builtin_amdgcn_logf)
__device__ __forceinline__ float flog2(float x) { return __builtin_amdgcn_logf(x); }
#else
__device__ __forceinline__ float flog2(float x) { return __log2f(x); }
#endif

// ---------------- Kernel A: per-block partial column minima ----------------
__global__ __launch_bounds__(256) void k_min(const float* __restrict__ phi,
                                             float* __restrict__ ws) {
    __shared__ float sm[1024];
    const int tid = threadIdx.x;
    const int g = blockIdx.x * 256 + tid;
    const float4* __restrict__ p4 = (const float4*)phi;
    float4 m = p4[g];
    #pragma unroll
    for (int k = 1; k < 16; ++k) {
        float4 v = p4[g + k * 65536];
        m.x = fminf(m.x, v.x); m.y = fminf(m.y, v.y);
        m.z = fminf(m.z, v.z); m.w = fminf(m.w, v.w);
    }
    sm[tid * 4 + 0] = m.x; sm[tid * 4 + 1] = m.y;
    sm[tid * 4 + 2] = m.z; sm[tid * 4 + 3] = m.w;
    __syncthreads();
    #pragma unroll
    for (int s = 128; s >= 8; s >>= 1) {
        if (tid < s) {
            sm[tid * 4 + 0] = fminf(sm[tid * 4 + 0], sm[(tid + s) * 4 + 0]);
            sm[tid * 4 + 1] = fminf(sm[tid * 4 + 1], sm[(tid + s) * 4 + 1]);
            sm[tid * 4 + 2] = fminf(sm[tid * 4 + 2], sm[(tid + s) * 4 + 2]);
            sm[tid * 4 + 3] = fminf(sm[tid * 4 + 3], sm[(tid + s) * 4 + 3]);
        }
        __syncthreads();
    }
    if (tid < 8) {
        #pragma unroll
        for (int s2 = 0; s2 < 4; ++s2)
            ws[2048 + blockIdx.x * 32 + tid * 4 + s2] = sm[tid * 4 + s2];
    }
}

// ------- Kernel B: final min reduce + Gamma symmetrization into ws --------
__global__ __launch_bounds__(256) void k_prep(const float* __restrict__ Gamma,
                                              float* __restrict__ ws) {
    __shared__ float sm[256];
    const int tid = threadIdx.x;
    const int c = tid & 31, h = tid >> 5;      // 8 groups of 32 partial-blocks
    float m = INFINITY;
    #pragma unroll
    for (int b = 0; b < 32; ++b)
        m = fminf(m, ws[2048 + (h * 32 + b) * 32 + c]);
    sm[tid] = m;
    __syncthreads();
    if (tid < 32) {
        float mm = sm[tid];
        #pragma unroll
        for (int g2 = 1; g2 < 8; ++g2) mm = fminf(mm, sm[g2 * 32 + tid]);
        ws[1024 + tid] = mm - EC;
    }
    // Gsym[i][j] = Gamma[min(i,j), max(i,j)]
    #pragma unroll
    for (int k = 0; k < 4; ++k) {
        int idx = tid + 256 * k;
        int i = idx >> 5, j = idx & 31;
        int lo = min(i, j), hi = i + j - lo;
        ws[idx] = Gamma[lo * 32 + hi];
    }
}

// ---------------- Kernel C: main (row-per-thread, fully unrolled) ----------
// 512 blocks x 256 threads. Each thread owns one row, everything in
// registers: L[32]=log2(phic), ph[32]=phic, xs[32]=-t*energy. The 32x32
// (i,j) loop is fully unrolled so all register indexing is static and the
// Gamma rows are wave-uniform s_loads the compiler can pipeline ahead.
// No LDS, no barriers.
__global__ __launch_bounds__(256) void k_main(const float* __restrict__ phi,
                                              const float* __restrict__ w,
                                              const float* __restrict__ ws,
                                              float* __restrict__ out) {
    const int tid = threadIdx.x;
    const size_t row = (size_t)blockIdx.x * 256 + tid;
    const float* __restrict__ pr = phi + row * NM;
    const float* __restrict__ mme = ws + 1024;   // mode_min - e (uniform)

    float L[32], ph[32];
    #pragma unroll
    for (int k = 0; k < 8; ++k) {
        float4 v = ((const float4*)pr)[k];
        // phic = max(phi - mode_min + e, e) = max(phi - (mode_min - e), e)
        ph[4 * k + 0] = fmaxf(v.x - mme[4 * k + 0], EC);
        ph[4 * k + 1] = fmaxf(v.y - mme[4 * k + 1], EC);
        ph[4 * k + 2] = fmaxf(v.z - mme[4 * k + 2], EC);
        ph[4 * k + 3] = fmaxf(v.w - mme[4 * k + 3], EC);
        L[4 * k + 0] = flog2(ph[4 * k + 0]);
        L[4 * k + 1] = flog2(ph[4 * k + 1]);
        L[4 * k + 2] = flog2(ph[4 * k + 2]);
        L[4 * k + 3] = flog2(ph[4 * k + 3]);
    }

    float xs[32];
    #pragma unroll
    for (int i = 0; i < 32; ++i) {
        const float Li = L[i];
        float acc0 = 0.f, acc1 = 0.f, acc2 = 0.f, acc3 = 0.f;
        #pragma unroll
        for (int j = 0; j < 32; j += 4) {
            // phic_i^g * phic_j^(1-g) = 2^(L_j + g*(L_i - L_j))
            acc0 += fexp2(fmaf(ws[i * 32 + j + 0], Li - L[j + 0], L[j + 0]));
            acc1 += fexp2(fmaf(ws[i * 32 + j + 1], Li - L[j + 1], L[j + 1]));
            acc2 += fexp2(fmaf(ws[i * 32 + j + 2], Li - L[j + 2], L[j + 2]));
            acc3 += fexp2(fmaf(ws[i * 32 + j + 3], Li - L[j + 3], L[j + 3]));
        }
        // fullsum's diagonal term == phic_i, so off-sum + (1+w)*phic = full + w*phic
        xs[i] = -TS * ((((acc0 + acc1) + (acc2 + acc3)) + w[i] * ph[i]));
    }

    float m = xs[0];
    #pragma unroll
    for (int i = 1; i < 32; ++i) m = fmaxf(m, xs[i]);
    float p[32];
    float s = 0.f;
    #pragma unroll
    for (int i = 0; i < 32; ++i) { p[i] = fexp2((xs[i] - m) * L2E); s += p[i]; }
    const float inv = 1.0f / s;
    const float lns = flog2(s) * LN2F;   // ln(s)

    float* __restrict__ oa = out + row * NM;
    float* __restrict__ ol = out + (size_t)NB * NM + row * NM;
    #pragma unroll
    for (int k = 0; k < 8; ++k) {
        float4 a4 = { p[4 * k + 0] * inv, p[4 * k + 1] * inv,
                      p[4 * k + 2] * inv, p[4 * k + 3] * inv };
        float4 l4 = { (xs[4 * k + 0] - m) - lns, (xs[4 * k + 1] - m) - lns,
                      (xs[4 * k + 2] - m) - lns, (xs[4 * k + 3] - m) - lns };
        ((float4*)oa)[k] = a4;
        ((float4*)ol)[k] = l4;
    }
}

extern "C" void kernel_launch(void* const* d_in, const int* in_sizes, int n_in,
                              void* d_out, int out_size, void* d_ws, size_t ws_size,
                              hipStream_t stream) {
    (void)in_sizes; (void)n_in; (void)out_size; (void)ws_size;
    const float* phi   = (const float*)d_in[0];
    const float* Gamma = (const float*)d_in[1];
    const float* w     = (const float*)d_in[2];
    float* out = (float*)d_out;
    float* wsf = (float*)d_ws;

    k_min<<<256, 256, 0, stream>>>(phi, wsf);
    k_prep<<<1, 256, 0, stream>>>(Gamma, wsf);
    k_main<<<512, 256, 0, stream>>>(phi, w, wsf, out);
}

// Round 3
// 108.203 us; speedup vs baseline: 1.1702x; 1.0158x over previous
//
#include <hip/hip_runtime.h>
#include <math.h>

#define NB 131072
#define NM 32
#define EC 2.7182818284590452f
#define TS 0.17677669529663687f   // 1/sqrt(32)
#define L2E 1.4426950408889634f
#define LN2F 0.6931471805599453f

// ws layout (floats):
//   [0, 1024)        : Gsym (symmetrized Gamma, row-major)
//   [1024, 1056)     : mode_min[c] - EC   (pre-subtracted)
//   [2048, 2048+8192): per-block partial column mins (256 blocks x 32 cols)

#if __has_builtin(__builtin_amdgcn_exp2f)
__device__ __forceinline__ float fexp2(float x) { return __builtin_amdgcn_exp2f(x); }
#else
__device__ __forceinline__ float fexp2(float x) { return exp2f(x); }
#endif
#if __has_builtin(__builtin_amdgcn_logf)
__device__ __forceinline__ float flog2(float x) { return __builtin_amdgcn_logf(x); }
#else
__device__ __forceinline__ float flog2(float x) { return __log2f(x); }
#endif

// ---------------- Kernel A: per-block partial column minima ----------------
__global__ __launch_bounds__(256) void k_min(const float* __restrict__ phi,
                                             float* __restrict__ ws) {
    __shared__ float sm[1024];
    const int tid = threadIdx.x;
    const int g = blockIdx.x * 256 + tid;
    const float4* __restrict__ p4 = (const float4*)phi;
    float4 m = p4[g];
    #pragma unroll
    for (int k = 1; k < 16; ++k) {
        float4 v = p4[g + k * 65536];
        m.x = fminf(m.x, v.x); m.y = fminf(m.y, v.y);
        m.z = fminf(m.z, v.z); m.w = fminf(m.w, v.w);
    }
    sm[tid * 4 + 0] = m.x; sm[tid * 4 + 1] = m.y;
    sm[tid * 4 + 2] = m.z; sm[tid * 4 + 3] = m.w;
    __syncthreads();
    #pragma unroll
    for (int s = 128; s >= 8; s >>= 1) {
        if (tid < s) {
            sm[tid * 4 + 0] = fminf(sm[tid * 4 + 0], sm[(tid + s) * 4 + 0]);
            sm[tid * 4 + 1] = fminf(sm[tid * 4 + 1], sm[(tid + s) * 4 + 1]);
            sm[tid * 4 + 2] = fminf(sm[tid * 4 + 2], sm[(tid + s) * 4 + 2]);
            sm[tid * 4 + 3] = fminf(sm[tid * 4 + 3], sm[(tid + s) * 4 + 3]);
        }
        __syncthreads();
    }
    if (tid < 8) {
        #pragma unroll
        for (int s2 = 0; s2 < 4; ++s2)
            ws[2048 + blockIdx.x * 32 + tid * 4 + s2] = sm[tid * 4 + s2];
    }
}

// ------- Kernel B: final min reduce + Gamma symmetrization into ws --------
__global__ __launch_bounds__(256) void k_prep(const float* __restrict__ Gamma,
                                              float* __restrict__ ws) {
    __shared__ float sm[256];
    const int tid = threadIdx.x;
    const int c = tid & 31, h = tid >> 5;      // 8 groups of 32 partial-blocks
    float m = INFINITY;
    #pragma unroll
    for (int b = 0; b < 32; ++b)
        m = fminf(m, ws[2048 + (h * 32 + b) * 32 + c]);
    sm[tid] = m;
    __syncthreads();
    if (tid < 32) {
        float mm = sm[tid];
        #pragma unroll
        for (int g2 = 1; g2 < 8; ++g2) mm = fminf(mm, sm[g2 * 32 + tid]);
        ws[1024 + tid] = mm - EC;
    }
    // Gsym[i][j] = Gamma[min(i,j), max(i,j)]
    #pragma unroll
    for (int k = 0; k < 4; ++k) {
        int idx = tid + 256 * k;
        int i = idx >> 5, j = idx & 31;
        int lo = min(i, j), hi = i + j - lo;
        ws[idx] = Gamma[lo * 32 + hi];
    }
}

// ---------------- Kernel C: main (row-per-thread) --------------------------
// 512 blocks x 256 threads, one row per thread. L[32] stays in REGISTERS
// (all j-indexing static). The only dynamically-indexed values (L_i at
// iteration i, and x_i) go through a 32 KB same-thread LDS mirror — one
// ds_read + one ds_write per i-iteration, conflict-free (consecutive lanes,
// 2 lanes/bank). Outer i-loop pinned rolled so the compiler never demotes
// the register arrays to scratch (R2's VGPR=56 spill bug). Gamma row and
// w[i] are wave-uniform -> s_load broadcasts.
__global__ __launch_bounds__(256) void k_main(const float* __restrict__ phi,
                                              const float* __restrict__ w,
                                              const float* __restrict__ ws,
                                              float* __restrict__ out) {
    __shared__ float sL[32 * 256];
    const int tid = threadIdx.x;
    const size_t row = (size_t)blockIdx.x * 256 + tid;
    const float* __restrict__ pr = phi + row * NM;
    const float* __restrict__ mme = ws + 1024;   // mode_min - e (uniform)

    float L[32];
    #pragma unroll
    for (int k = 0; k < 8; ++k) {
        float4 v = ((const float4*)pr)[k];
        // phic = max(phi - mode_min + e, e) = max(phi - (mode_min - e), e)
        float a0 = fmaxf(v.x - mme[4 * k + 0], EC);
        float a1 = fmaxf(v.y - mme[4 * k + 1], EC);
        float a2 = fmaxf(v.z - mme[4 * k + 2], EC);
        float a3 = fmaxf(v.w - mme[4 * k + 3], EC);
        L[4 * k + 0] = flog2(a0); L[4 * k + 1] = flog2(a1);
        L[4 * k + 2] = flog2(a2); L[4 * k + 3] = flog2(a3);
    }
    #pragma unroll
    for (int j = 0; j < 32; ++j) sL[j * 256 + tid] = L[j];
    // no __syncthreads: sL slots are strictly same-thread

    #pragma unroll 1
    for (int i = 0; i < 32; ++i) {
        const float Li = sL[i * 256 + tid];          // dynamic i -> LDS
        const float wi = w[i];                       // uniform s_load
        const float* __restrict__ g = ws + i * 32;   // uniform s_load row
        float acc0 = 0.f, acc1 = 0.f, acc2 = 0.f, acc3 = 0.f;
        #pragma unroll
        for (int j = 0; j < 32; j += 4) {
            // phic_i^g * phic_j^(1-g) = 2^(L_j + g*(L_i - L_j))
            acc0 += fexp2(fmaf(g[j + 0], Li - L[j + 0], L[j + 0]));
            acc1 += fexp2(fmaf(g[j + 1], Li - L[j + 1], L[j + 1]));
            acc2 += fexp2(fmaf(g[j + 2], Li - L[j + 2], L[j + 2]));
            acc3 += fexp2(fmaf(g[j + 3], Li - L[j + 3], L[j + 3]));
        }
        // fullsum's diagonal term == phic_i = 2^Li, so
        // off-sum + (1+w)*phic = fullsum + w*phic
        const float e = ((acc0 + acc1) + (acc2 + acc3)) + wi * fexp2(Li);
        sL[i * 256 + tid] = -TS * e;                 // Li consumed; reuse slot
    }

    float xs[32];
    #pragma unroll
    for (int i = 0; i < 32; ++i) xs[i] = sL[i * 256 + tid];
    float m = xs[0];
    #pragma unroll
    for (int i = 1; i < 32; ++i) m = fmaxf(m, xs[i]);
    float p[32];
    float s = 0.f;
    #pragma unroll
    for (int i = 0; i < 32; ++i) { p[i] = fexp2((xs[i] - m) * L2E); s += p[i]; }
    const float inv = 1.0f / s;
    const float lns = flog2(s) * LN2F;   // ln(s)

    float* __restrict__ oa = out + row * NM;
    float* __restrict__ ol = out + (size_t)NB * NM + row * NM;
    #pragma unroll
    for (int k = 0; k < 8; ++k) {
        float4 a4 = { p[4 * k + 0] * inv, p[4 * k + 1] * inv,
                      p[4 * k + 2] * inv, p[4 * k + 3] * inv };
        float4 l4 = { (xs[4 * k + 0] - m) - lns, (xs[4 * k + 1] - m) - lns,
                      (xs[4 * k + 2] - m) - lns, (xs[4 * k + 3] - m) - lns };
        ((float4*)oa)[k] = a4;
        ((float4*)ol)[k] = l4;
    }
}

extern "C" void kernel_launch(void* const* d_in, const int* in_sizes, int n_in,
                              void* d_out, int out_size, void* d_ws, size_t ws_size,
                              hipStream_t stream) {
    (void)in_sizes; (void)n_in; (void)out_size; (void)ws_size;
    const float* phi   = (const float*)d_in[0];
    const float* Gamma = (const float*)d_in[1];
    const float* w     = (const float*)d_in[2];
    float* out = (float*)d_out;
    float* wsf = (float*)d_ws;

    k_min<<<256, 256, 0, stream>>>(phi, wsf);
    k_prep<<<1, 256, 0, stream>>>(Gamma, wsf);
    k_main<<<512, 256, 0, stream>>>(phi, w, wsf, out);
}